// Round 2
// baseline (15789.854 us; speedup 1.0000x reference)
//
#include <hip/hip_runtime.h>
#include <hip/hip_bf16.h>

typedef __hip_bfloat16 bf16;
typedef __bf16 bf16x8 __attribute__((ext_vector_type(8)));
typedef __bf16 bf16x4 __attribute__((ext_vector_type(4)));
typedef float f32x4 __attribute__((ext_vector_type(4)));

#define B_      256
#define S_      128
#define HID_    768
#define EMB_    128
#define FF_     3072
#define LAYERS_ 12
#define HEADS_  12
#define DH_     64
#define M_TOK   (B_ * S_)   // 32768

__device__ inline float b2f(bf16 v) { return __bfloat162float(v); }
__device__ inline bf16  f2b(float v) { return __float2bfloat16(v); }

__device__ inline float wave_sum(float v) {
#pragma unroll
  for (int o = 32; o > 0; o >>= 1) v += __shfl_xor(v, o, 64);
  return v;
}

__device__ inline float gelu_exact(float x) {
  return 0.5f * x * (1.0f + erff(x * 0.70710678118654752f));
}

__device__ inline void glds16(const bf16* g, bf16* l) {
  __builtin_amdgcn_global_load_lds(
      (const __attribute__((address_space(1))) void*)g,
      (__attribute__((address_space(3))) void*)l, 16, 0, 0);
}

// ---------------------------------------------------------------------------
// C = A (MxK bf16 rm) * Bt^T (Bt NxK bf16 rm) + bias; mode 0: bias,
// mode 1: bias+gelu, mode 2: bias+posenc.  M%128==0, N%128==0, K%64==0.
// Tile 128x128, BK=64. LDS layout: 16 slabs/matrix, slab s=(r16,ks), 1KB each,
// element addr = s*512 + lane*8  (conflict-free linear ds_read_b128).
// MFMA called with swapped operands so each lane owns 4 consecutive cols.
// ---------------------------------------------------------------------------
__global__ __launch_bounds__(256)
void gemm_bt(const bf16* __restrict__ A, const bf16* __restrict__ Bt,
             const float* __restrict__ bias, bf16* __restrict__ C,
             int M, int N, int K, int mode)
{
  __shared__ __align__(16) bf16 As[128 * 64];
  __shared__ __align__(16) bf16 Bs[128 * 64];
  const int tid  = threadIdx.x;
  const int wave = tid >> 6, lane = tid & 63;
  const int m0 = blockIdx.y * 128, n0 = blockIdx.x * 128;
  const int lr = lane & 15, lkg = lane >> 4;

  const bf16* gA[4]; const bf16* gB[4];
  bf16 *lA[4], *lB[4];
#pragma unroll
  for (int c = 0; c < 4; c++) {
    const int s = wave * 4 + c;
    const int row = (s >> 1) * 16 + lr;          // row within 128-tile
    const int col = (s & 1) * 32 + lkg * 8;      // k within 64-slab
    gA[c] = A  + (size_t)(m0 + row) * K + col;
    gB[c] = Bt + (size_t)(n0 + row) * K + col;
    lA[c] = As + s * 512;
    lB[c] = Bs + s * 512;
  }

  const int rm = (wave >> 1) * 64;   // wave tile origin in M
  const int rn = (wave & 1) * 64;    // wave tile origin in N
  const int aSlab = (wave >> 1) * 4; // r16 base for A frags
  const int bSlab = (wave & 1) * 4;  // r16 base for B frags

  const f32x4 zacc = {0.f, 0.f, 0.f, 0.f};
  f32x4 acc[4][4];
#pragma unroll
  for (int i = 0; i < 4; i++)
#pragma unroll
    for (int j = 0; j < 4; j++) acc[i][j] = zacc;

  for (int k0 = 0; k0 < K; k0 += 64) {
#pragma unroll
    for (int c = 0; c < 4; c++) glds16(gA[c] + k0, lA[c]);
#pragma unroll
    for (int c = 0; c < 4; c++) glds16(gB[c] + k0, lB[c]);
    __syncthreads();
#pragma unroll
    for (int kk = 0; kk < 2; kk++) {
      bf16x8 af[4], bfr[4];
#pragma unroll
      for (int i = 0; i < 4; i++)
        af[i] = *(const bf16x8*)&As[((aSlab + i) * 2 + kk) * 512 + lane * 8];
#pragma unroll
      for (int j = 0; j < 4; j++)
        bfr[j] = *(const bf16x8*)&Bs[((bSlab + j) * 2 + kk) * 512 + lane * 8];
#pragma unroll
      for (int i = 0; i < 4; i++)
#pragma unroll
        for (int j = 0; j < 4; j++)
          acc[i][j] = __builtin_amdgcn_mfma_f32_16x16x32_bf16(bfr[j], af[i], acc[i][j], 0, 0, 0);
    }
    __syncthreads();
  }

  // D mapping (swapped operands): m = m0+rm+i*16+(lane&15),
  //                               n = n0+rn+j*16+4*(lane>>4)+r
#pragma unroll
  for (int i = 0; i < 4; i++) {
    const int m = m0 + rm + i * 16 + lr;
    bf16* crow = C + (size_t)m * N;
#pragma unroll
    for (int j = 0; j < 4; j++) {
      const int nb = n0 + rn + j * 16 + (lkg << 2);
      const float4 bv = *(const float4*)&bias[nb];
      const float* bvp = (const float*)&bv;
      bf16 h[4];
#pragma unroll
      for (int r = 0; r < 4; r++) {
        float t = acc[i][j][r] + bvp[r];
        if (mode == 1) t = gelu_exact(t);
        if (mode == 2) {
          t = gelu_exact(t);
          const int col = nb + r;
          const int srow = m & (S_ - 1);
          const int i2 = col & ~1;
          const float div = expf(-9.210340371976184f * (float)i2 * (1.0f / (float)HID_));
          const float ang = (float)srow * div;
          t += (col & 1) ? cosf(ang) : sinf(ang);
        }
        h[r] = f2b(t);
      }
      *(uint2*)&crow[nb] = *(const uint2*)h;
    }
  }
}

// ---------------------------------------------------------------------------
// fp32 (K,N) -> bf16 (N,K) convert + transpose, standalone. block (32,8)
// ---------------------------------------------------------------------------
__device__ inline void convtrans_tile(const float* __restrict__ src, bf16* __restrict__ dst,
                                      int K, int N, int bx, int by)
{
  __shared__ bf16 t[32][33];
  const int n0 = bx * 32, k0 = by * 32;
  const int tx = threadIdx.x, ty = threadIdx.y;
#pragma unroll
  for (int i = 0; i < 4; i++)
    t[ty + i * 8][tx] = f2b(src[(size_t)(k0 + ty + i * 8) * N + n0 + tx]);
  __syncthreads();
#pragma unroll
  for (int i = 0; i < 4; i++)
    dst[(size_t)(n0 + ty + i * 8) * K + k0 + tx] = t[tx][ty + i * 8];
}

__global__ __launch_bounds__(256)
void convtrans(const float* __restrict__ src, bf16* __restrict__ dst, int K, int N)
{
  convtrans_tile(src, dst, K, N, blockIdx.x, blockIdx.y);
}

// fused per-layer weight conversion: qkv, ao, ff1, ff2 in one dispatch.
// ranges: [0,1728) qkv 72x24 | [1728,2304) ao 24x24 | [2304,4608) ff1 96x24 |
// [4608,6912) ff2 24x96
__global__ __launch_bounds__(256)
void convtrans4(const float* __restrict__ qkvW, const float* __restrict__ aoW,
                const float* __restrict__ ff1W, const float* __restrict__ ff2W,
                bf16* __restrict__ dqkv, bf16* __restrict__ dao,
                bf16* __restrict__ dff1, bf16* __restrict__ dff2)
{
  const int bid = blockIdx.x;
  if (bid < 1728) {
    convtrans_tile(qkvW, dqkv, 768, 2304, bid % 72, bid / 72);
  } else if (bid < 2304) {
    const int t = bid - 1728;
    convtrans_tile(aoW, dao, 768, 768, t % 24, t / 24);
  } else if (bid < 4608) {
    const int t = bid - 2304;
    convtrans_tile(ff1W, dff1, 768, 3072, t % 96, t / 96);
  } else {
    const int t = bid - 4608;
    convtrans_tile(ff2W, dff2, 3072, 768, t % 24, t / 24);
  }
}

// ---------------------------------------------------------------------------
// sliding-window attention: one block per (b, head), 128 threads (row each).
// LDS chunk-major [c][s][8] so fragment reads are lane-linear (no conflicts).
// ---------------------------------------------------------------------------
__global__ __launch_bounds__(128)
void attn_kernel(const bf16* __restrict__ qkv, bf16* __restrict__ ctx)
{
  const int bh = blockIdx.x;
  const int b = bh / HEADS_, h = bh % HEADS_;
  __shared__ __align__(16) bf16 qs[8 * 128 * 8];
  __shared__ __align__(16) bf16 ks[8 * 128 * 8];
  __shared__ __align__(16) bf16 vs[8 * 128 * 8];
  const int tid = threadIdx.x;
  const bf16* base = qkv + (size_t)b * S_ * (3 * HID_) + h * DH_;
  for (int it = tid; it < 1024; it += 128) {
    const int s = it & 127, c = it >> 7;
    const size_t go = (size_t)s * (3 * HID_) + c * 8;
    *(uint4*)&qs[it * 8] = *(const uint4*)&base[go];
    *(uint4*)&ks[it * 8] = *(const uint4*)&base[go + HID_];
    *(uint4*)&vs[it * 8] = *(const uint4*)&base[go + 2 * HID_];
  }
  __syncthreads();
  const int i = tid;
  bf16* out = ctx + (size_t)(b * S_ + i) * HID_ + h * DH_;
  if (i < 116) {
    float d[13];
#pragma unroll
    for (int jj = 0; jj < 13; jj++) d[jj] = 0.f;
#pragma unroll
    for (int c = 0; c < 8; c++) {
      const bf16x8 q8 = *(const bf16x8*)&qs[c * 1024 + i * 8];
#pragma unroll
      for (int jj = 0; jj < 13; jj++) {
        if (jj == 6) continue;
        const bf16x8 k8 = *(const bf16x8*)&ks[c * 1024 + (i + jj) * 8];
        float s = 0.f;
#pragma unroll
        for (int e = 0; e < 8; e++) s += (float)q8[e] * (float)k8[e];
        d[jj] += s;
      }
    }
    float mx = -1e30f;
#pragma unroll
    for (int jj = 0; jj < 13; jj++) {
      if (jj == 6) continue;
      d[jj] *= 0.125f;
      mx = fmaxf(mx, d[jj]);
    }
    float l = 0.f;
#pragma unroll
    for (int jj = 0; jj < 13; jj++) {
      if (jj == 6) { d[jj] = 0.f; continue; }
      d[jj] = expf(d[jj] - mx);
      l += d[jj];
    }
    const float inv = 1.f / l;
#pragma unroll
    for (int jj = 0; jj < 13; jj++) d[jj] *= inv;
#pragma unroll
    for (int c = 0; c < 8; c++) {
      float o8[8];
#pragma unroll
      for (int e = 0; e < 8; e++) o8[e] = 0.f;
#pragma unroll
      for (int jj = 0; jj < 13; jj++) {
        if (jj == 6) continue;
        const float pj = d[jj];
        const bf16x8 v8 = *(const bf16x8*)&vs[c * 1024 + (i + jj) * 8];
#pragma unroll
        for (int e = 0; e < 8; e++) o8[e] += pj * (float)v8[e];
      }
      bf16 hh[8];
#pragma unroll
      for (int e = 0; e < 8; e++) hh[e] = f2b(o8[e]);
      *(uint4*)&out[c * 8] = *(const uint4*)hh;
    }
  } else {
    const uint4 z = {0, 0, 0, 0};
#pragma unroll
    for (int c = 0; c < 8; c++) *(uint4*)&out[c * 8] = z;
  }
}

// ---------------------------------------------------------------------------
// out = LN(x + y) over 768.  wave per row, 4 rows per block.
// ---------------------------------------------------------------------------
__global__ __launch_bounds__(256)
void add_ln_kernel(const bf16* __restrict__ x, const bf16* __restrict__ y,
                   const float* __restrict__ g, const float* __restrict__ bta,
                   bf16* __restrict__ out)
{
  const int row  = blockIdx.x * 4 + (threadIdx.x >> 6);
  const int lane = threadIdx.x & 63;
  const size_t base = (size_t)row * HID_;
  const bf16x8 a8 = *(const bf16x8*)&x[base + lane * 8];
  const bf16x8 b8 = *(const bf16x8*)&y[base + lane * 8];
  const bf16x4 a4 = *(const bf16x4*)&x[base + 512 + lane * 4];
  const bf16x4 b4 = *(const bf16x4*)&y[base + 512 + lane * 4];
  float v[12];
#pragma unroll
  for (int e = 0; e < 8; e++) v[e] = (float)a8[e] + (float)b8[e];
#pragma unroll
  for (int e = 0; e < 4; e++) v[8 + e] = (float)a4[e] + (float)b4[e];
  float s = 0.f, ss = 0.f;
#pragma unroll
  for (int e = 0; e < 12; e++) { s += v[e]; ss += v[e] * v[e]; }
  s = wave_sum(s); ss = wave_sum(ss);
  const float mean = s * (1.f / (float)HID_);
  const float var  = ss * (1.f / (float)HID_) - mean * mean;
  const float rs = rsqrtf(var + 1e-5f);
  bf16 h8[8]; bf16 h4[4];
#pragma unroll
  for (int e = 0; e < 8; e++) {
    const int col = lane * 8 + e;
    h8[e] = f2b((v[e] - mean) * rs * g[col] + bta[col]);
  }
#pragma unroll
  for (int e = 0; e < 4; e++) {
    const int col = 512 + lane * 4 + e;
    h4[e] = f2b((v[8 + e] - mean) * rs * g[col] + bta[col]);
  }
  *(uint4*)&out[base + lane * 8]       = *(const uint4*)h8;
  *(uint2*)&out[base + 512 + lane * 4] = *(const uint2*)h4;
}

// ---------------------------------------------------------------------------
// out[token] = LN(W[idx[token]]) over 128.  wave per token.
// ---------------------------------------------------------------------------
__global__ __launch_bounds__(256)
void gather_ln128(const int* __restrict__ idx, const float* __restrict__ W,
                  const float* __restrict__ g, const float* __restrict__ bta,
                  bf16* __restrict__ out)
{
  const int token = blockIdx.x * 4 + (threadIdx.x >> 6);
  const int lane = threadIdx.x & 63;
  const int row = idx[token];
  const float* src = W + (size_t)row * 128;
  const float a = src[lane], c = src[lane + 64];
  const float s  = wave_sum(a + c);
  const float ss = wave_sum(a * a + c * c);
  const float mean = s * (1.f / 128.f);
  const float var  = ss * (1.f / 128.f) - mean * mean;
  const float rs = rsqrtf(var + 1e-5f);
  bf16* o = out + (size_t)token * 128;
  o[lane]      = f2b((a - mean) * rs * g[lane] + bta[lane]);
  o[lane + 64] = f2b((c - mean) * rs * g[lane + 64] + bta[lane + 64]);
}

__global__ __launch_bounds__(256)
void ln128_bf16(const bf16* __restrict__ in, const float* __restrict__ g,
                const float* __restrict__ bta, bf16* __restrict__ out)
{
  const int token = blockIdx.x * 4 + (threadIdx.x >> 6);
  const int lane = threadIdx.x & 63;
  const bf16* src = in + (size_t)token * 128;
  const float a = b2f(src[lane]), c = b2f(src[lane + 64]);
  const float s  = wave_sum(a + c);
  const float ss = wave_sum(a * a + c * c);
  const float mean = s * (1.f / 128.f);
  const float var  = ss * (1.f / 128.f) - mean * mean;
  const float rs = rsqrtf(var + 1e-5f);
  bf16* o = out + (size_t)token * 128;
  o[lane]      = f2b((a - mean) * rs * g[lane] + bta[lane]);
  o[lane + 64] = f2b((c - mean) * rs * g[lane + 64] + bta[lane + 64]);
}

// ---------------------------------------------------------------------------
// loss: grid (B, 2).
// ---------------------------------------------------------------------------
__global__ __launch_bounds__(256)
void loss_kernel(const bf16* __restrict__ out_z, const bf16* __restrict__ preds,
                 const bf16* __restrict__ neg_e, float* __restrict__ out)
{
  const int b = blockIdx.x;
  const int which = blockIdx.y;
  __shared__ __align__(16) bf16 zo[128 * 128];
  __shared__ __align__(16) bf16 mt[128 * 128];
  const bf16* msrc = which ? neg_e : preds;
  const uint4* gz = (const uint4*)(out_z + (size_t)b * 16384);
  const uint4* gm = (const uint4*)(msrc + (size_t)b * 16384);
  for (int it = threadIdx.x; it < 2048; it += 256) {
    ((uint4*)zo)[it] = gz[it];
    ((uint4*)mt)[it] = gm[it];
  }
  __syncthreads();
  float local = 0.f;
  for (int it = threadIdx.x; it < 232; it += 256) {
    const int i = it >> 1;
    const int sub = it & 1;
    const int c0 = i + (sub ? 7 : 0);
    const bf16* zr = &zo[i * 128];
    float accv = 0.f;
    for (int jj = 0; jj < 6; jj++) {
      const bf16* mr = &mt[(c0 + jj) * 128];
      float dsum = 0.f;
#pragma unroll
      for (int cc = 0; cc < 16; cc++) {
        const bf16x8 z8 = *(const bf16x8*)&zr[cc * 8];
        const bf16x8 m8 = *(const bf16x8*)&mr[cc * 8];
#pragma unroll
        for (int e = 0; e < 8; e++) dsum += (float)z8[e] * (float)m8[e];
      }
      accv += dsum;
    }
    const float mean = accv * (1.f / 6.f);
    const float xin = which ? mean : -mean;
    local += fmaxf(xin, 0.f) + log1pf(expf(-fabsf(xin)));
  }
  local = wave_sum(local);
  if ((threadIdx.x & 63) == 0)
    atomicAdd(out, local * (1.f / 118784.f));
}

__global__ void zero_kernel(float* p) { p[0] = 0.f; }

// ---------------------------------------------------------------------------
extern "C" void kernel_launch(void* const* d_in, const int* in_sizes, int n_in,
                              void* d_out, int out_size, void* d_ws, size_t ws_size,
                              hipStream_t stream)
{
  (void)in_sizes; (void)n_in; (void)out_size; (void)ws_size;
  const int*   seq     = (const int*)  d_in[0];
  const int*   neg_idx = (const int*)  d_in[1];
  const float* embed_W = (const float*)d_in[2];
  const float* embed_g = (const float*)d_in[3];
  const float* embed_b = (const float*)d_in[4];
  const float* proj_W  = (const float*)d_in[5];
  const float* proj_b  = (const float*)d_in[6];
  const float* qkv_W   = (const float*)d_in[7];
  const float* qkv_b   = (const float*)d_in[8];
  const float* ao_W    = (const float*)d_in[9];
  const float* ao_b    = (const float*)d_in[10];
  const float* ln1_g   = (const float*)d_in[11];
  const float* ln1_b   = (const float*)d_in[12];
  const float* ff1_W   = (const float*)d_in[13];
  const float* ff1_b   = (const float*)d_in[14];
  const float* ff2_W   = (const float*)d_in[15];
  const float* ff2_b   = (const float*)d_in[16];
  const float* ln2_g   = (const float*)d_in[17];
  const float* ln2_b   = (const float*)d_in[18];
  const float* head_W  = (const float*)d_in[19];
  const float* head_b  = (const float*)d_in[20];
  const float* head_g  = (const float*)d_in[21];
  const float* head_bt = (const float*)d_in[22];
  const float* oemb_W  = (const float*)d_in[23];
  const float* oemb_g  = (const float*)d_in[24];
  const float* oemb_b  = (const float*)d_in[25];
  float* out = (float*)d_out;

  char* ws = (char*)d_ws;
  size_t off = 0;
  auto alloc = [&](size_t bytes) -> char* {
    char* p = ws + off;
    off += (bytes + 255) & ~(size_t)255;
    return p;
  };
  bf16* wt_qkv  = (bf16*)alloc((size_t)2304 * 768 * 2);
  bf16* wt_ao   = (bf16*)alloc((size_t)768 * 768 * 2);
  bf16* wt_ff1  = (bf16*)alloc((size_t)3072 * 768 * 2);
  bf16* wt_ff2  = (bf16*)alloc((size_t)768 * 3072 * 2);
  bf16* wt_proj = (bf16*)alloc((size_t)768 * 128 * 2);
  bf16* wt_head = (bf16*)alloc((size_t)128 * 768 * 2);
  bf16* zbuf    = (bf16*)alloc((size_t)M_TOK * 128 * 2);
  bf16* x       = (bf16*)alloc((size_t)M_TOK * 768 * 2);
  bf16* big     = (bf16*)alloc((size_t)M_TOK * 3072 * 2);
  bf16* ctx     = (bf16*)alloc((size_t)M_TOK * 768 * 2);
  bf16* ybuf    = (bf16*)alloc((size_t)M_TOK * 768 * 2);
  bf16* p0      = (bf16*)alloc((size_t)M_TOK * 128 * 2);
  bf16* preds   = (bf16*)alloc((size_t)M_TOK * 128 * 2);
  bf16* outz    = (bf16*)alloc((size_t)M_TOK * 128 * 2);
  bf16* nege    = (bf16*)alloc((size_t)M_TOK * 128 * 2);

  const dim3 tb(32, 8);

  convtrans<<<dim3(768 / 32, 128 / 32), tb, 0, stream>>>(proj_W, wt_proj, 128, 768);
  convtrans<<<dim3(128 / 32, 768 / 32), tb, 0, stream>>>(head_W, wt_head, 768, 128);

  gather_ln128<<<M_TOK / 4, 256, 0, stream>>>(seq, embed_W, embed_g, embed_b, zbuf);
  gemm_bt<<<dim3(768 / 128, M_TOK / 128), 256, 0, stream>>>(zbuf, wt_proj, proj_b, x,
                                                            M_TOK, 768, 128, 2);

  for (int l = 0; l < LAYERS_; ++l) {
    convtrans4<<<6912, tb, 0, stream>>>(
        qkv_W + (size_t)l * 768 * 2304, ao_W + (size_t)l * 768 * 768,
        ff1_W + (size_t)l * 768 * 3072, ff2_W + (size_t)l * 3072 * 768,
        wt_qkv, wt_ao, wt_ff1, wt_ff2);

    gemm_bt<<<dim3(2304 / 128, M_TOK / 128), 256, 0, stream>>>(x, wt_qkv, qkv_b + l * 2304, big,
                                                               M_TOK, 2304, 768, 0);
    attn_kernel<<<B_ * HEADS_, 128, 0, stream>>>(big, ctx);
    gemm_bt<<<dim3(768 / 128, M_TOK / 128), 256, 0, stream>>>(ctx, wt_ao, ao_b + l * 768, ybuf,
                                                              M_TOK, 768, 768, 0);
    add_ln_kernel<<<M_TOK / 4, 256, 0, stream>>>(x, ybuf, ln1_g + l * 768, ln1_b + l * 768, x);
    gemm_bt<<<dim3(3072 / 128, M_TOK / 128), 256, 0, stream>>>(x, wt_ff1, ff1_b + l * 3072, big,
                                                               M_TOK, 3072, 768, 1);
    gemm_bt<<<dim3(768 / 128, M_TOK / 128), 256, 0, stream>>>(big, wt_ff2, ff2_b + l * 768, ybuf,
                                                              M_TOK, 768, 3072, 0);
    add_ln_kernel<<<M_TOK / 4, 256, 0, stream>>>(x, ybuf, ln2_g + l * 768, ln2_b + l * 768, x);
  }

  gemm_bt<<<dim3(1, M_TOK / 128), 256, 0, stream>>>(x, wt_head, head_b, p0, M_TOK, 128, 768, 0);
  ln128_bf16<<<M_TOK / 4, 256, 0, stream>>>(p0, head_g, head_bt, preds);
  gather_ln128<<<M_TOK / 4, 256, 0, stream>>>(seq, oemb_W, oemb_g, oemb_b, outz);
  gather_ln128<<<M_TOK / 4, 256, 0, stream>>>(neg_idx, oemb_W, oemb_g, oemb_b, nege);
  zero_kernel<<<1, 1, 0, stream>>>(out);
  loss_kernel<<<dim3(B_, 2), 256, 0, stream>>>(outz, preds, nege, out);
}

// Round 3
// 12037.173 us; speedup vs baseline: 1.3118x; 1.3118x over previous
//
#include <hip/hip_runtime.h>
#include <hip/hip_bf16.h>

typedef __hip_bfloat16 bf16;
typedef __bf16 bf16x8 __attribute__((ext_vector_type(8)));
typedef __bf16 bf16x4 __attribute__((ext_vector_type(4)));
typedef float f32x4 __attribute__((ext_vector_type(4)));

#define B_      256
#define S_      128
#define HID_    768
#define EMB_    128
#define FF_     3072
#define LAYERS_ 12
#define HEADS_  12
#define DH_     64
#define M_TOK   (B_ * S_)   // 32768

__device__ inline float b2f(bf16 v) { return __bfloat162float(v); }
__device__ inline bf16  f2b(float v) { return __float2bfloat16(v); }

__device__ inline float wave_sum(float v) {
#pragma unroll
  for (int o = 32; o > 0; o >>= 1) v += __shfl_xor(v, o, 64);
  return v;
}

__device__ inline float gelu_exact(float x) {
  return 0.5f * x * (1.0f + erff(x * 0.70710678118654752f));
}

__device__ inline void glds16(const bf16* g, bf16* l) {
  __builtin_amdgcn_global_load_lds(
      (const __attribute__((address_space(1))) void*)g,
      (__attribute__((address_space(3))) void*)l, 16, 0, 0);
}

// ---------------------------------------------------------------------------
// C = A (MxK bf16 rm) * Bt^T (Bt NxK bf16 rm) + bias; mode 0: bias,
// mode 1: bias+gelu, mode 2: bias+gelu+posenc.  M%128==0, N%128==0, K%32==0.
// Tile 128x128, BK=32, 16 KB LDS/matrix-pair. Staging is lane-monotonic
// (4 consecutive lanes = one 64 B global segment) with a 16 B-slot XOR
// swizzle (slot = cg ^ ((row>>1)&3)) so fragment ds_read_b128 is
// conflict-free: 8-lane groups tile the 8 LDS quads exactly.
// MFMA operands swapped so each lane owns 4 consecutive output cols.
// ---------------------------------------------------------------------------
__global__ __launch_bounds__(256)
void gemm_bt(const bf16* __restrict__ A, const bf16* __restrict__ Bt,
             const float* __restrict__ bias, bf16* __restrict__ C,
             int M, int N, int K, int mode)
{
  __shared__ __align__(16) bf16 As[128 * 32];
  __shared__ __align__(16) bf16 Bs[128 * 32];
  const int tid  = threadIdx.x;
  const int wave = tid >> 6, lane = tid & 63;
  const int m0 = blockIdx.y * 128, n0 = blockIdx.x * 128;

  // staging: 8 chunks (16 rows x 32 k, 1 KB) per matrix; wave w owns 2w, 2w+1
  const int srow = lane >> 2;                    // row within chunk
  const int scg  = lane & 3;                     // 16B slot within row
  const int ssw  = (scg ^ ((srow >> 1) & 3)) * 8; // swizzled source col (elems)
  const int c0 = wave * 2;
  const bf16* ga0 = A  + (size_t)(m0 + c0 * 16       + srow) * K + ssw;
  const bf16* ga1 = A  + (size_t)(m0 + (c0 + 1) * 16 + srow) * K + ssw;
  const bf16* gb0 = Bt + (size_t)(n0 + c0 * 16       + srow) * K + ssw;
  const bf16* gb1 = Bt + (size_t)(n0 + (c0 + 1) * 16 + srow) * K + ssw;
  bf16* lA0 = As + c0 * 512;  bf16* lA1 = As + (c0 + 1) * 512;
  bf16* lB0 = Bs + c0 * 512;  bf16* lB1 = Bs + (c0 + 1) * 512;

  const int lr  = lane & 15;
  const int lkg = lane >> 4;
  const int fsw = (lkg ^ ((lr >> 1) & 3)) * 8;   // swizzled fragment col (elems)
  const int rm = (wave >> 1) * 64;
  const int rn = (wave & 1) * 64;

  const f32x4 zacc = {0.f, 0.f, 0.f, 0.f};
  f32x4 acc[4][4];
#pragma unroll
  for (int i = 0; i < 4; i++)
#pragma unroll
    for (int j = 0; j < 4; j++) acc[i][j] = zacc;

  for (int k0 = 0; k0 < K; k0 += 32) {
    glds16(ga0 + k0, lA0);
    glds16(ga1 + k0, lA1);
    glds16(gb0 + k0, lB0);
    glds16(gb1 + k0, lB1);
    __syncthreads();
    bf16x8 af[4], bfr[4];
#pragma unroll
    for (int i = 0; i < 4; i++)
      af[i]  = *(const bf16x8*)&As[(rm + i * 16 + lr) * 32 + fsw];
#pragma unroll
    for (int j = 0; j < 4; j++)
      bfr[j] = *(const bf16x8*)&Bs[(rn + j * 16 + lr) * 32 + fsw];
#pragma unroll
    for (int i = 0; i < 4; i++)
#pragma unroll
      for (int j = 0; j < 4; j++)
        acc[i][j] = __builtin_amdgcn_mfma_f32_16x16x32_bf16(bfr[j], af[i], acc[i][j], 0, 0, 0);
    __syncthreads();
  }

  // D mapping (swapped operands): m = m0+rm+i*16+(lane&15),
  //                               n = n0+rn+j*16+4*(lane>>4)+r
#pragma unroll
  for (int i = 0; i < 4; i++) {
    const int m = m0 + rm + i * 16 + lr;
    bf16* crow = C + (size_t)m * N;
#pragma unroll
    for (int j = 0; j < 4; j++) {
      const int nb = n0 + rn + j * 16 + (lkg << 2);
      const float4 bv = *(const float4*)&bias[nb];
      const float* bvp = (const float*)&bv;
      bf16 h[4];
#pragma unroll
      for (int r = 0; r < 4; r++) {
        float t = acc[i][j][r] + bvp[r];
        if (mode == 1) t = gelu_exact(t);
        if (mode == 2) {
          t = gelu_exact(t);
          const int col = nb + r;
          const int srow2 = m & (S_ - 1);
          const int i2 = col & ~1;
          const float div = expf(-9.210340371976184f * (float)i2 * (1.0f / (float)HID_));
          const float ang = (float)srow2 * div;
          t += (col & 1) ? cosf(ang) : sinf(ang);
        }
        h[r] = f2b(t);
      }
      *(uint2*)&crow[nb] = *(const uint2*)h;
    }
  }
}

// ---------------------------------------------------------------------------
// fp32 (K,N) -> bf16 (N,K) convert + transpose. block (32,8)
// ---------------------------------------------------------------------------
__device__ inline void convtrans_tile(const float* __restrict__ src, bf16* __restrict__ dst,
                                      int K, int N, int bx, int by)
{
  __shared__ bf16 t[32][33];
  const int n0 = bx * 32, k0 = by * 32;
  const int tx = threadIdx.x, ty = threadIdx.y;
#pragma unroll
  for (int i = 0; i < 4; i++)
    t[ty + i * 8][tx] = f2b(src[(size_t)(k0 + ty + i * 8) * N + n0 + tx]);
  __syncthreads();
#pragma unroll
  for (int i = 0; i < 4; i++)
    dst[(size_t)(n0 + ty + i * 8) * K + k0 + tx] = t[tx][ty + i * 8];
}

__global__ __launch_bounds__(256)
void convtrans(const float* __restrict__ src, bf16* __restrict__ dst, int K, int N)
{
  convtrans_tile(src, dst, K, N, blockIdx.x, blockIdx.y);
}

// fused per-layer weight conversion: qkv, ao, ff1, ff2 in one dispatch.
__global__ __launch_bounds__(256)
void convtrans4(const float* __restrict__ qkvW, const float* __restrict__ aoW,
                const float* __restrict__ ff1W, const float* __restrict__ ff2W,
                bf16* __restrict__ dqkv, bf16* __restrict__ dao,
                bf16* __restrict__ dff1, bf16* __restrict__ dff2)
{
  const int bid = blockIdx.x;
  if (bid < 1728) {
    convtrans_tile(qkvW, dqkv, 768, 2304, bid % 72, bid / 72);
  } else if (bid < 2304) {
    const int t = bid - 1728;
    convtrans_tile(aoW, dao, 768, 768, t % 24, t / 24);
  } else if (bid < 4608) {
    const int t = bid - 2304;
    convtrans_tile(ff1W, dff1, 768, 3072, t % 96, t / 96);
  } else {
    const int t = bid - 4608;
    convtrans_tile(ff2W, dff2, 3072, 768, t % 24, t / 24);
  }
}

// ---------------------------------------------------------------------------
// sliding-window attention: one block per (b, head), 128 threads (row each).
// ---------------------------------------------------------------------------
__global__ __launch_bounds__(128)
void attn_kernel(const bf16* __restrict__ qkv, bf16* __restrict__ ctx)
{
  const int bh = blockIdx.x;
  const int b = bh / HEADS_, h = bh % HEADS_;
  __shared__ __align__(16) bf16 qs[8 * 128 * 8];
  __shared__ __align__(16) bf16 ks[8 * 128 * 8];
  __shared__ __align__(16) bf16 vs[8 * 128 * 8];
  const int tid = threadIdx.x;
  const bf16* base = qkv + (size_t)b * S_ * (3 * HID_) + h * DH_;
  for (int it = tid; it < 1024; it += 128) {
    const int s = it & 127, c = it >> 7;
    const size_t go = (size_t)s * (3 * HID_) + c * 8;
    *(uint4*)&qs[it * 8] = *(const uint4*)&base[go];
    *(uint4*)&ks[it * 8] = *(const uint4*)&base[go + HID_];
    *(uint4*)&vs[it * 8] = *(const uint4*)&base[go + 2 * HID_];
  }
  __syncthreads();
  const int i = tid;
  bf16* out = ctx + (size_t)(b * S_ + i) * HID_ + h * DH_;
  if (i < 116) {
    float d[13];
#pragma unroll
    for (int jj = 0; jj < 13; jj++) d[jj] = 0.f;
#pragma unroll
    for (int c = 0; c < 8; c++) {
      const bf16x8 q8 = *(const bf16x8*)&qs[c * 1024 + i * 8];
#pragma unroll
      for (int jj = 0; jj < 13; jj++) {
        if (jj == 6) continue;
        const bf16x8 k8 = *(const bf16x8*)&ks[c * 1024 + (i + jj) * 8];
        float s = 0.f;
#pragma unroll
        for (int e = 0; e < 8; e++) s += (float)q8[e] * (float)k8[e];
        d[jj] += s;
      }
    }
    float mx = -1e30f;
#pragma unroll
    for (int jj = 0; jj < 13; jj++) {
      if (jj == 6) continue;
      d[jj] *= 0.125f;
      mx = fmaxf(mx, d[jj]);
    }
    float l = 0.f;
#pragma unroll
    for (int jj = 0; jj < 13; jj++) {
      if (jj == 6) { d[jj] = 0.f; continue; }
      d[jj] = expf(d[jj] - mx);
      l += d[jj];
    }
    const float inv = 1.f / l;
#pragma unroll
    for (int jj = 0; jj < 13; jj++) d[jj] *= inv;
#pragma unroll
    for (int c = 0; c < 8; c++) {
      float o8[8];
#pragma unroll
      for (int e = 0; e < 8; e++) o8[e] = 0.f;
#pragma unroll
      for (int jj = 0; jj < 13; jj++) {
        if (jj == 6) continue;
        const float pj = d[jj];
        const bf16x8 v8 = *(const bf16x8*)&vs[c * 1024 + (i + jj) * 8];
#pragma unroll
        for (int e = 0; e < 8; e++) o8[e] += pj * (float)v8[e];
      }
      bf16 hh[8];
#pragma unroll
      for (int e = 0; e < 8; e++) hh[e] = f2b(o8[e]);
      *(uint4*)&out[c * 8] = *(const uint4*)hh;
    }
  } else {
    const uint4 z = {0, 0, 0, 0};
#pragma unroll
    for (int c = 0; c < 8; c++) *(uint4*)&out[c * 8] = z;
  }
}

// ---------------------------------------------------------------------------
// out = LN(x + y) over 768.  wave per row, 4 rows per block.
// ---------------------------------------------------------------------------
__global__ __launch_bounds__(256)
void add_ln_kernel(const bf16* __restrict__ x, const bf16* __restrict__ y,
                   const float* __restrict__ g, const float* __restrict__ bta,
                   bf16* __restrict__ out)
{
  const int row  = blockIdx.x * 4 + (threadIdx.x >> 6);
  const int lane = threadIdx.x & 63;
  const size_t base = (size_t)row * HID_;
  const bf16x8 a8 = *(const bf16x8*)&x[base + lane * 8];
  const bf16x8 b8 = *(const bf16x8*)&y[base + lane * 8];
  const bf16x4 a4 = *(const bf16x4*)&x[base + 512 + lane * 4];
  const bf16x4 b4 = *(const bf16x4*)&y[base + 512 + lane * 4];
  float v[12];
#pragma unroll
  for (int e = 0; e < 8; e++) v[e] = (float)a8[e] + (float)b8[e];
#pragma unroll
  for (int e = 0; e < 4; e++) v[8 + e] = (float)a4[e] + (float)b4[e];
  float s = 0.f, ss = 0.f;
#pragma unroll
  for (int e = 0; e < 12; e++) { s += v[e]; ss += v[e] * v[e]; }
  s = wave_sum(s); ss = wave_sum(ss);
  const float mean = s * (1.f / (float)HID_);
  const float var  = ss * (1.f / (float)HID_) - mean * mean;
  const float rs = rsqrtf(var + 1e-5f);
  bf16 h8[8]; bf16 h4[4];
#pragma unroll
  for (int e = 0; e < 8; e++) {
    const int col = lane * 8 + e;
    h8[e] = f2b((v[e] - mean) * rs * g[col] + bta[col]);
  }
#pragma unroll
  for (int e = 0; e < 4; e++) {
    const int col = 512 + lane * 4 + e;
    h4[e] = f2b((v[8 + e] - mean) * rs * g[col] + bta[col]);
  }
  *(uint4*)&out[base + lane * 8]       = *(const uint4*)h8;
  *(uint2*)&out[base + 512 + lane * 4] = *(const uint2*)h4;
}

// ---------------------------------------------------------------------------
// out[token] = LN(W[idx[token]]) over 128.  wave per token.
// ---------------------------------------------------------------------------
__global__ __launch_bounds__(256)
void gather_ln128(const int* __restrict__ idx, const float* __restrict__ W,
                  const float* __restrict__ g, const float* __restrict__ bta,
                  bf16* __restrict__ out)
{
  const int token = blockIdx.x * 4 + (threadIdx.x >> 6);
  const int lane = threadIdx.x & 63;
  const int row = idx[token];
  const float* src = W + (size_t)row * 128;
  const float a = src[lane], c = src[lane + 64];
  const float s  = wave_sum(a + c);
  const float ss = wave_sum(a * a + c * c);
  const float mean = s * (1.f / 128.f);
  const float var  = ss * (1.f / 128.f) - mean * mean;
  const float rs = rsqrtf(var + 1e-5f);
  bf16* o = out + (size_t)token * 128;
  o[lane]      = f2b((a - mean) * rs * g[lane] + bta[lane]);
  o[lane + 64] = f2b((c - mean) * rs * g[lane + 64] + bta[lane + 64]);
}

__global__ __launch_bounds__(256)
void ln128_bf16(const bf16* __restrict__ in, const float* __restrict__ g,
                const float* __restrict__ bta, bf16* __restrict__ out)
{
  const int token = blockIdx.x * 4 + (threadIdx.x >> 6);
  const int lane = threadIdx.x & 63;
  const bf16* src = in + (size_t)token * 128;
  const float a = b2f(src[lane]), c = b2f(src[lane + 64]);
  const float s  = wave_sum(a + c);
  const float ss = wave_sum(a * a + c * c);
  const float mean = s * (1.f / 128.f);
  const float var  = ss * (1.f / 128.f) - mean * mean;
  const float rs = rsqrtf(var + 1e-5f);
  bf16* o = out + (size_t)token * 128;
  o[lane]      = f2b((a - mean) * rs * g[lane] + bta[lane]);
  o[lane + 64] = f2b((c - mean) * rs * g[lane + 64] + bta[lane + 64]);
}

// ---------------------------------------------------------------------------
// loss: grid (B, 2).
// ---------------------------------------------------------------------------
__global__ __launch_bounds__(256)
void loss_kernel(const bf16* __restrict__ out_z, const bf16* __restrict__ preds,
                 const bf16* __restrict__ neg_e, float* __restrict__ out)
{
  const int b = blockIdx.x;
  const int which = blockIdx.y;
  __shared__ __align__(16) bf16 zo[128 * 128];
  __shared__ __align__(16) bf16 mt[128 * 128];
  const bf16* msrc = which ? neg_e : preds;
  const uint4* gz = (const uint4*)(out_z + (size_t)b * 16384);
  const uint4* gm = (const uint4*)(msrc + (size_t)b * 16384);
  for (int it = threadIdx.x; it < 2048; it += 256) {
    ((uint4*)zo)[it] = gz[it];
    ((uint4*)mt)[it] = gm[it];
  }
  __syncthreads();
  float local = 0.f;
  for (int it = threadIdx.x; it < 232; it += 256) {
    const int i = it >> 1;
    const int sub = it & 1;
    const int c0 = i + (sub ? 7 : 0);
    const bf16* zr = &zo[i * 128];
    float accv = 0.f;
    for (int jj = 0; jj < 6; jj++) {
      const bf16* mr = &mt[(c0 + jj) * 128];
      float dsum = 0.f;
#pragma unroll
      for (int cc = 0; cc < 16; cc++) {
        const bf16x8 z8 = *(const bf16x8*)&zr[cc * 8];
        const bf16x8 m8 = *(const bf16x8*)&mr[cc * 8];
#pragma unroll
        for (int e = 0; e < 8; e++) dsum += (float)z8[e] * (float)m8[e];
      }
      accv += dsum;
    }
    const float mean = accv * (1.f / 6.f);
    const float xin = which ? mean : -mean;
    local += fmaxf(xin, 0.f) + log1pf(expf(-fabsf(xin)));
  }
  local = wave_sum(local);
  if ((threadIdx.x & 63) == 0)
    atomicAdd(out, local * (1.f / 118784.f));
}

__global__ void zero_kernel(float* p) { p[0] = 0.f; }

// ---------------------------------------------------------------------------
extern "C" void kernel_launch(void* const* d_in, const int* in_sizes, int n_in,
                              void* d_out, int out_size, void* d_ws, size_t ws_size,
                              hipStream_t stream)
{
  (void)in_sizes; (void)n_in; (void)out_size; (void)ws_size;
  const int*   seq     = (const int*)  d_in[0];
  const int*   neg_idx = (const int*)  d_in[1];
  const float* embed_W = (const float*)d_in[2];
  const float* embed_g = (const float*)d_in[3];
  const float* embed_b = (const float*)d_in[4];
  const float* proj_W  = (const float*)d_in[5];
  const float* proj_b  = (const float*)d_in[6];
  const float* qkv_W   = (const float*)d_in[7];
  const float* qkv_b   = (const float*)d_in[8];
  const float* ao_W    = (const float*)d_in[9];
  const float* ao_b    = (const float*)d_in[10];
  const float* ln1_g   = (const float*)d_in[11];
  const float* ln1_b   = (const float*)d_in[12];
  const float* ff1_W   = (const float*)d_in[13];
  const float* ff1_b   = (const float*)d_in[14];
  const float* ff2_W   = (const float*)d_in[15];
  const float* ff2_b   = (const float*)d_in[16];
  const float* ln2_g   = (const float*)d_in[17];
  const float* ln2_b   = (const float*)d_in[18];
  const float* head_W  = (const float*)d_in[19];
  const float* head_b  = (const float*)d_in[20];
  const float* head_g  = (const float*)d_in[21];
  const float* head_bt = (const float*)d_in[22];
  const float* oemb_W  = (const float*)d_in[23];
  const float* oemb_g  = (const float*)d_in[24];
  const float* oemb_b  = (const float*)d_in[25];
  float* out = (float*)d_out;

  char* ws = (char*)d_ws;
  size_t off = 0;
  auto alloc = [&](size_t bytes) -> char* {
    char* p = ws + off;
    off += (bytes + 255) & ~(size_t)255;
    return p;
  };
  bf16* wt_qkv  = (bf16*)alloc((size_t)2304 * 768 * 2);
  bf16* wt_ao   = (bf16*)alloc((size_t)768 * 768 * 2);
  bf16* wt_ff1  = (bf16*)alloc((size_t)3072 * 768 * 2);
  bf16* wt_ff2  = (bf16*)alloc((size_t)768 * 3072 * 2);
  bf16* wt_proj = (bf16*)alloc((size_t)768 * 128 * 2);
  bf16* wt_head = (bf16*)alloc((size_t)128 * 768 * 2);
  bf16* zbuf    = (bf16*)alloc((size_t)M_TOK * 128 * 2);
  bf16* x       = (bf16*)alloc((size_t)M_TOK * 768 * 2);
  bf16* big     = (bf16*)alloc((size_t)M_TOK * 3072 * 2);
  bf16* ctx     = (bf16*)alloc((size_t)M_TOK * 768 * 2);
  bf16* ybuf    = (bf16*)alloc((size_t)M_TOK * 768 * 2);
  bf16* p0      = (bf16*)alloc((size_t)M_TOK * 128 * 2);
  bf16* preds   = (bf16*)alloc((size_t)M_TOK * 128 * 2);
  bf16* outz    = (bf16*)alloc((size_t)M_TOK * 128 * 2);
  bf16* nege    = (bf16*)alloc((size_t)M_TOK * 128 * 2);

  const dim3 tb(32, 8);

  convtrans<<<dim3(768 / 32, 128 / 32), tb, 0, stream>>>(proj_W, wt_proj, 128, 768);
  convtrans<<<dim3(128 / 32, 768 / 32), tb, 0, stream>>>(head_W, wt_head, 768, 128);

  gather_ln128<<<M_TOK / 4, 256, 0, stream>>>(seq, embed_W, embed_g, embed_b, zbuf);
  gemm_bt<<<dim3(768 / 128, M_TOK / 128), 256, 0, stream>>>(zbuf, wt_proj, proj_b, x,
                                                            M_TOK, 768, 128, 2);

  for (int l = 0; l < LAYERS_; ++l) {
    convtrans4<<<6912, tb, 0, stream>>>(
        qkv_W + (size_t)l * 768 * 2304, ao_W + (size_t)l * 768 * 768,
        ff1_W + (size_t)l * 768 * 3072, ff2_W + (size_t)l * 3072 * 768,
        wt_qkv, wt_ao, wt_ff1, wt_ff2);

    gemm_bt<<<dim3(2304 / 128, M_TOK / 128), 256, 0, stream>>>(x, wt_qkv, qkv_b + l * 2304, big,
                                                               M_TOK, 2304, 768, 0);
    attn_kernel<<<B_ * HEADS_, 128, 0, stream>>>(big, ctx);
    gemm_bt<<<dim3(768 / 128, M_TOK / 128), 256, 0, stream>>>(ctx, wt_ao, ao_b + l * 768, ybuf,
                                                              M_TOK, 768, 768, 0);
    add_ln_kernel<<<M_TOK / 4, 256, 0, stream>>>(x, ybuf, ln1_g + l * 768, ln1_b + l * 768, x);
    gemm_bt<<<dim3(3072 / 128, M_TOK / 128), 256, 0, stream>>>(x, wt_ff1, ff1_b + l * 3072, big,
                                                               M_TOK, 3072, 768, 1);
    gemm_bt<<<dim3(768 / 128, M_TOK / 128), 256, 0, stream>>>(big, wt_ff2, ff2_b + l * 768, ybuf,
                                                              M_TOK, 768, 3072, 0);
    add_ln_kernel<<<M_TOK / 4, 256, 0, stream>>>(x, ybuf, ln2_g + l * 768, ln2_b + l * 768, x);
  }

  gemm_bt<<<dim3(1, M_TOK / 128), 256, 0, stream>>>(x, wt_head, head_b, p0, M_TOK, 128, 768, 0);
  ln128_bf16<<<M_TOK / 4, 256, 0, stream>>>(p0, head_g, head_bt, preds);
  gather_ln128<<<M_TOK / 4, 256, 0, stream>>>(seq, oemb_W, oemb_g, oemb_b, outz);
  gather_ln128<<<M_TOK / 4, 256, 0, stream>>>(neg_idx, oemb_W, oemb_g, oemb_b, nege);
  zero_kernel<<<1, 1, 0, stream>>>(out);
  loss_kernel<<<dim3(B_, 2), 256, 0, stream>>>(outz, preds, nege, out);
}